// Round 3
// baseline (6641.668 us; speedup 1.0000x reference)
//
#include <hip/hip_runtime.h>
#include <hip/hip_bf16.h>

#define CDIM 32
#define KCLS 20
#define NBASE 12
#define PPROP 1024
#define TBLW 20   // 18 sem cols (2..19) + binary + count

__device__ __forceinline__ void lds_addf(float* p, float v) {
  __hip_atomic_fetch_add(p, v, __ATOMIC_RELAXED, __HIP_MEMORY_SCOPE_WORKGROUP);
}
__device__ __forceinline__ void glb_addf(float* p, float v) {
  __hip_atomic_fetch_add(p, v, __ATOMIC_RELAXED, __HIP_MEMORY_SCOPE_AGENT);
}

// ---------------- scores: open-vocab renormalized softmax-gate ----------------
__global__ void k_scores(const float* __restrict__ sem, const float* __restrict__ bin,
                         float* __restrict__ out, int n) {
  int stride = gridDim.x * blockDim.x;
  for (int i = blockIdx.x * blockDim.x + threadIdx.x; i < n; i += stride) {
    const float4* r = reinterpret_cast<const float4*>(sem + (size_t)i * KCLS);
    float s[KCLS];
    float4 v;
    v = r[0]; s[0]=v.x; s[1]=v.y; s[2]=v.z; s[3]=v.w;
    v = r[1]; s[4]=v.x; s[5]=v.y; s[6]=v.z; s[7]=v.w;
    v = r[2]; s[8]=v.x; s[9]=v.y; s[10]=v.z; s[11]=v.w;
    v = r[3]; s[12]=v.x; s[13]=v.y; s[14]=v.z; s[15]=v.w;
    v = r[4]; s[16]=v.x; s[17]=v.y; s[18]=v.z; s[19]=v.w;

    float m12 = s[0];
#pragma unroll
    for (int k = 1; k < NBASE; k++) m12 = fmaxf(m12, s[k]);
    float sum12 = 0.f;
#pragma unroll
    for (int k = 0; k < NBASE; k++) { s[k] = __expf(s[k] - m12); sum12 += s[k]; }

    float m8 = s[NBASE];
#pragma unroll
    for (int k = NBASE + 1; k < KCLS; k++) m8 = fmaxf(m8, s[k]);
    float sum8 = 0.f;
#pragma unroll
    for (int k = NBASE; k < KCLS; k++) { s[k] = __expf(s[k] - m8); sum8 += s[k]; }

    float sig = 1.f / (1.f + __expf(-bin[i]));
    // analytic: renormalization denominator == 1, fold gate/softmax-denoms
    float cb = sig / sum12;
    float cn = (1.f - sig) / sum8;
#pragma unroll
    for (int k = 0; k < NBASE; k++) s[k] *= cb;
#pragma unroll
    for (int k = NBASE; k < KCLS; k++) s[k] *= cn;

    float4* o = reinterpret_cast<float4*>(out + (size_t)i * KCLS);
    o[0] = make_float4(s[0], s[1], s[2], s[3]);
    o[1] = make_float4(s[4], s[5], s[6], s[7]);
    o[2] = make_float4(s[8], s[9], s[10], s[11]);
    o[3] = make_float4(s[12], s[13], s[14], s[15]);
    o[4] = make_float4(s[16], s[17], s[18], s[19]);
  }
}

// ---------------- proposal scatter-mean accumulation ----------------
__global__ __launch_bounds__(512) void k_scatter(const float* __restrict__ sem,
    const float* __restrict__ bin, const int* __restrict__ pidx,
    const int* __restrict__ pid, float* __restrict__ acc, int m) {
  __shared__ float tbl[PPROP * TBLW];  // 80 KiB
  for (int t = threadIdx.x; t < PPROP * TBLW; t += blockDim.x) tbl[t] = 0.f;
  __syncthreads();

  int stride = gridDim.x * blockDim.x;
  for (int i = blockIdx.x * blockDim.x + threadIdx.x; i < m; i += stride) {
    int q = pidx[i];
    int p = pid[i];
    const float* row = sem + (size_t)q * KCLS;
    float2 a  = *reinterpret_cast<const float2*>(row + 2);
    float4 c0 = *reinterpret_cast<const float4*>(row + 4);
    float4 c1 = *reinterpret_cast<const float4*>(row + 8);
    float4 c2 = *reinterpret_cast<const float4*>(row + 12);
    float4 c3 = *reinterpret_cast<const float4*>(row + 16);
    float bv = bin[q];
    float* t = tbl + p * TBLW;
    lds_addf(t + 0, a.x);  lds_addf(t + 1, a.y);
    lds_addf(t + 2, c0.x); lds_addf(t + 3, c0.y); lds_addf(t + 4, c0.z); lds_addf(t + 5, c0.w);
    lds_addf(t + 6, c1.x); lds_addf(t + 7, c1.y); lds_addf(t + 8, c1.z); lds_addf(t + 9, c1.w);
    lds_addf(t +10, c2.x); lds_addf(t +11, c2.y); lds_addf(t +12, c2.z); lds_addf(t +13, c2.w);
    lds_addf(t +14, c3.x); lds_addf(t +15, c3.y); lds_addf(t +16, c3.z); lds_addf(t +17, c3.w);
    lds_addf(t +18, bv);
    lds_addf(t +19, 1.f);
  }
  __syncthreads();
  for (int t = threadIdx.x; t < PPROP * TBLW; t += blockDim.x) {
    float v = tbl[t];
    if (v != 0.f) glb_addf(acc + t, v);
  }
}

// ---------------- mask/iou heads + BN statistics over h1 = feats@W1+b1 ----------------
// Weights staged in LDS (broadcast ds_read_b128, no bank conflicts); 2 points per
// thread so each weight fetch feeds 8 FMAs. Round-1/2 lesson: uniform-indexed
// global weight reads re-fetch 8 KB/point through scalar cache -> latency-bound.
__global__ __launch_bounds__(256, 1) void k_heads(const float* __restrict__ feats,
    const float* __restrict__ W1,  const float* __restrict__ b1,
    const float* __restrict__ Wm1, const float* __restrict__ bm1,
    const float* __restrict__ Wm2, const float* __restrict__ bm2,
    const float* __restrict__ Wi,  const float* __restrict__ bi,
    float* __restrict__ mask_out, float* __restrict__ iou_out,
    float* __restrict__ stats, int n) {
  __shared__ float sWm1[CDIM * CDIM];
  __shared__ float sW1[CDIM * CDIM];
  __shared__ float sBm1[CDIM], sB1[CDIM], sWm2[CDIM], sWi[CDIM];

  int t = threadIdx.x;
  for (int idx = t; idx < CDIM * CDIM; idx += 256) { sWm1[idx] = Wm1[idx]; sW1[idx] = W1[idx]; }
  if (t < CDIM) { sBm1[t] = bm1[t]; sB1[t] = b1[t]; sWm2[t] = Wm2[t]; sWi[t] = Wi[t]; }
  __syncthreads();

  const float4* Wm14 = reinterpret_cast<const float4*>(sWm1);
  const float4* W14  = reinterpret_cast<const float4*>(sW1);
  const float4* Bm14 = reinterpret_cast<const float4*>(sBm1);
  const float4* B14  = reinterpret_cast<const float4*>(sB1);
  const float4* Wm24 = reinterpret_cast<const float4*>(sWm2);
  const float4* Wi4  = reinterpret_cast<const float4*>(sWi);

  float hs[CDIM], hq[CDIM];
#pragma unroll
  for (int j = 0; j < CDIM; j++) { hs[j] = 0.f; hq[j] = 0.f; }

  float bm2v = bm2[0], biv = bi[0];

  int total = gridDim.x * blockDim.x;
  for (int i = blockIdx.x * blockDim.x + t; i < n; i += 2 * total) {
    int i1 = i + total;
    bool has1 = i1 < n;

    float f0[CDIM], f1[CDIM];
    const float4* fr0 = reinterpret_cast<const float4*>(feats + (size_t)i * CDIM);
#pragma unroll
    for (int q = 0; q < 8; q++) {
      float4 v = fr0[q];
      f0[4*q] = v.x; f0[4*q+1] = v.y; f0[4*q+2] = v.z; f0[4*q+3] = v.w;
    }
    if (has1) {
      const float4* fr1 = reinterpret_cast<const float4*>(feats + (size_t)i1 * CDIM);
#pragma unroll
      for (int q = 0; q < 8; q++) {
        float4 v = fr1[q];
        f1[4*q] = v.x; f1[4*q+1] = v.y; f1[4*q+2] = v.z; f1[4*q+3] = v.w;
      }
    } else {
#pragma unroll
      for (int j = 0; j < CDIM; j++) f1[j] = 0.f;
    }

    // ---- mask head hidden: relu(f @ Wm1 + bm1) . Wm2 + bm2 ----
    float a0[CDIM], a1[CDIM];
#pragma unroll
    for (int q = 0; q < 8; q++) {
      float4 b = Bm14[q];
      a0[4*q]=b.x; a0[4*q+1]=b.y; a0[4*q+2]=b.z; a0[4*q+3]=b.w;
      a1[4*q]=b.x; a1[4*q+1]=b.y; a1[4*q+2]=b.z; a1[4*q+3]=b.w;
    }
#pragma unroll
    for (int c = 0; c < CDIM; c++) {
      float fc0 = f0[c], fc1 = f1[c];
#pragma unroll
      for (int q = 0; q < 8; q++) {
        float4 w = Wm14[c * 8 + q];
        a0[4*q]   = fmaf(fc0, w.x, a0[4*q]);
        a0[4*q+1] = fmaf(fc0, w.y, a0[4*q+1]);
        a0[4*q+2] = fmaf(fc0, w.z, a0[4*q+2]);
        a0[4*q+3] = fmaf(fc0, w.w, a0[4*q+3]);
        a1[4*q]   = fmaf(fc1, w.x, a1[4*q]);
        a1[4*q+1] = fmaf(fc1, w.y, a1[4*q+1]);
        a1[4*q+2] = fmaf(fc1, w.z, a1[4*q+2]);
        a1[4*q+3] = fmaf(fc1, w.w, a1[4*q+3]);
      }
    }
    float mk0 = bm2v, mk1 = bm2v, io0 = biv, io1 = biv;
#pragma unroll
    for (int q = 0; q < 8; q++) {
      float4 wm = Wm24[q];
      float4 wi = Wi4[q];
      mk0 = fmaf(fmaxf(a0[4*q],   0.f), wm.x, mk0);
      mk0 = fmaf(fmaxf(a0[4*q+1], 0.f), wm.y, mk0);
      mk0 = fmaf(fmaxf(a0[4*q+2], 0.f), wm.z, mk0);
      mk0 = fmaf(fmaxf(a0[4*q+3], 0.f), wm.w, mk0);
      mk1 = fmaf(fmaxf(a1[4*q],   0.f), wm.x, mk1);
      mk1 = fmaf(fmaxf(a1[4*q+1], 0.f), wm.y, mk1);
      mk1 = fmaf(fmaxf(a1[4*q+2], 0.f), wm.z, mk1);
      mk1 = fmaf(fmaxf(a1[4*q+3], 0.f), wm.w, mk1);
      io0 = fmaf(f0[4*q], wi.x, io0); io0 = fmaf(f0[4*q+1], wi.y, io0);
      io0 = fmaf(f0[4*q+2], wi.z, io0); io0 = fmaf(f0[4*q+3], wi.w, io0);
      io1 = fmaf(f1[4*q], wi.x, io1); io1 = fmaf(f1[4*q+1], wi.y, io1);
      io1 = fmaf(f1[4*q+2], wi.z, io1); io1 = fmaf(f1[4*q+3], wi.w, io1);
    }
    mask_out[i] = mk0; iou_out[i] = io0;
    if (has1) { mask_out[i1] = mk1; iou_out[i1] = io1; }

    // ---- h1 = f @ W1 + b1 for BN stats (reuse a0/a1) ----
#pragma unroll
    for (int q = 0; q < 8; q++) {
      float4 b = B14[q];
      a0[4*q]=b.x; a0[4*q+1]=b.y; a0[4*q+2]=b.z; a0[4*q+3]=b.w;
      a1[4*q]=b.x; a1[4*q+1]=b.y; a1[4*q+2]=b.z; a1[4*q+3]=b.w;
    }
#pragma unroll
    for (int c = 0; c < CDIM; c++) {
      float fc0 = f0[c], fc1 = f1[c];
#pragma unroll
      for (int q = 0; q < 8; q++) {
        float4 w = W14[c * 8 + q];
        a0[4*q]   = fmaf(fc0, w.x, a0[4*q]);
        a0[4*q+1] = fmaf(fc0, w.y, a0[4*q+1]);
        a0[4*q+2] = fmaf(fc0, w.z, a0[4*q+2]);
        a0[4*q+3] = fmaf(fc0, w.w, a0[4*q+3]);
        a1[4*q]   = fmaf(fc1, w.x, a1[4*q]);
        a1[4*q+1] = fmaf(fc1, w.y, a1[4*q+1]);
        a1[4*q+2] = fmaf(fc1, w.z, a1[4*q+2]);
        a1[4*q+3] = fmaf(fc1, w.w, a1[4*q+3]);
      }
    }
#pragma unroll
    for (int j = 0; j < CDIM; j++) { hs[j] += a0[j]; hq[j] = fmaf(a0[j], a0[j], hq[j]); }
    if (has1) {
#pragma unroll
      for (int j = 0; j < CDIM; j++) { hs[j] += a1[j]; hq[j] = fmaf(a1[j], a1[j], hq[j]); }
    }
  }

  __shared__ float red[2 * CDIM];
  __syncthreads();
  for (int q = t; q < 2 * CDIM; q += 256) red[q] = 0.f;
  __syncthreads();
#pragma unroll
  for (int j = 0; j < CDIM; j++) { lds_addf(&red[j], hs[j]); lds_addf(&red[CDIM + j], hq[j]); }
  __syncthreads();
  for (int q = t; q < 2 * CDIM; q += 256) glb_addf(&stats[q], red[q]);
}

// ---------------- tiny: fold BN stats into scale/shift ----------------
__global__ void k_bnprep(const float* __restrict__ stats,
                         const float* __restrict__ g1, const float* __restrict__ be1,
                         float* __restrict__ bnsc, float* __restrict__ bntc, float invN) {
  int j = threadIdx.x;
  if (j < CDIM) {
    float mu  = stats[j] * invN;
    float var = stats[CDIM + j] * invN - mu * mu;
    float isd = rsqrtf(var + 1e-4f);
    float sc = g1[j] * isd;
    bnsc[j] = sc;
    bntc[j] = be1[j] - mu * sc;
  }
}

// ---------------- pt_offsets: Linear->BN(precomputed sc/tc)->ReLU->Linear ----------------
__global__ __launch_bounds__(256, 1) void k_offsets(const float* __restrict__ feats,
    const float* __restrict__ W1, const float* __restrict__ b1,
    const float* __restrict__ W2, const float* __restrict__ b2,
    const float* __restrict__ bnsc, const float* __restrict__ bntc,
    float* __restrict__ out_off, int n) {
  __shared__ float sW1[CDIM * CDIM];
  __shared__ float sB1[CDIM], sSc[CDIM], sTc[CDIM];
  __shared__ float sW2x[CDIM], sW2y[CDIM], sW2z[CDIM];  // transposed for float4 reads

  int t = threadIdx.x;
  for (int idx = t; idx < CDIM * CDIM; idx += 256) sW1[idx] = W1[idx];
  if (t < CDIM) {
    sB1[t] = b1[t]; sSc[t] = bnsc[t]; sTc[t] = bntc[t];
    sW2x[t] = W2[t * 3 + 0]; sW2y[t] = W2[t * 3 + 1]; sW2z[t] = W2[t * 3 + 2];
  }
  __syncthreads();

  const float4* W14 = reinterpret_cast<const float4*>(sW1);
  const float4* B14 = reinterpret_cast<const float4*>(sB1);
  const float4* Sc4 = reinterpret_cast<const float4*>(sSc);
  const float4* Tc4 = reinterpret_cast<const float4*>(sTc);
  const float4* Wx4 = reinterpret_cast<const float4*>(sW2x);
  const float4* Wy4 = reinterpret_cast<const float4*>(sW2y);
  const float4* Wz4 = reinterpret_cast<const float4*>(sW2z);

  float b2x = b2[0], b2y = b2[1], b2z = b2[2];

  int total = gridDim.x * blockDim.x;
  for (int i = blockIdx.x * blockDim.x + t; i < n; i += 2 * total) {
    int i1 = i + total;
    bool has1 = i1 < n;

    float f0[CDIM], f1[CDIM];
    const float4* fr0 = reinterpret_cast<const float4*>(feats + (size_t)i * CDIM);
#pragma unroll
    for (int q = 0; q < 8; q++) {
      float4 v = fr0[q];
      f0[4*q] = v.x; f0[4*q+1] = v.y; f0[4*q+2] = v.z; f0[4*q+3] = v.w;
    }
    if (has1) {
      const float4* fr1 = reinterpret_cast<const float4*>(feats + (size_t)i1 * CDIM);
#pragma unroll
      for (int q = 0; q < 8; q++) {
        float4 v = fr1[q];
        f1[4*q] = v.x; f1[4*q+1] = v.y; f1[4*q+2] = v.z; f1[4*q+3] = v.w;
      }
    } else {
#pragma unroll
      for (int j = 0; j < CDIM; j++) f1[j] = 0.f;
    }

    float a0[CDIM], a1[CDIM];
#pragma unroll
    for (int q = 0; q < 8; q++) {
      float4 b = B14[q];
      a0[4*q]=b.x; a0[4*q+1]=b.y; a0[4*q+2]=b.z; a0[4*q+3]=b.w;
      a1[4*q]=b.x; a1[4*q+1]=b.y; a1[4*q+2]=b.z; a1[4*q+3]=b.w;
    }
#pragma unroll
    for (int c = 0; c < CDIM; c++) {
      float fc0 = f0[c], fc1 = f1[c];
#pragma unroll
      for (int q = 0; q < 8; q++) {
        float4 w = W14[c * 8 + q];
        a0[4*q]   = fmaf(fc0, w.x, a0[4*q]);
        a0[4*q+1] = fmaf(fc0, w.y, a0[4*q+1]);
        a0[4*q+2] = fmaf(fc0, w.z, a0[4*q+2]);
        a0[4*q+3] = fmaf(fc0, w.w, a0[4*q+3]);
        a1[4*q]   = fmaf(fc1, w.x, a1[4*q]);
        a1[4*q+1] = fmaf(fc1, w.y, a1[4*q+1]);
        a1[4*q+2] = fmaf(fc1, w.z, a1[4*q+2]);
        a1[4*q+3] = fmaf(fc1, w.w, a1[4*q+3]);
      }
    }

    float ox0 = b2x, oy0 = b2y, oz0 = b2z;
    float ox1 = b2x, oy1 = b2y, oz1 = b2z;
#pragma unroll
    for (int q = 0; q < 8; q++) {
      float4 sc = Sc4[q], tc = Tc4[q];
      float4 wx = Wx4[q], wy = Wy4[q], wz = Wz4[q];
      float y;
      y = fmaxf(fmaf(a0[4*q],   sc.x, tc.x), 0.f); ox0 = fmaf(y, wx.x, ox0); oy0 = fmaf(y, wy.x, oy0); oz0 = fmaf(y, wz.x, oz0);
      y = fmaxf(fmaf(a0[4*q+1], sc.y, tc.y), 0.f); ox0 = fmaf(y, wx.y, ox0); oy0 = fmaf(y, wy.y, oy0); oz0 = fmaf(y, wz.y, oz0);
      y = fmaxf(fmaf(a0[4*q+2], sc.z, tc.z), 0.f); ox0 = fmaf(y, wx.z, ox0); oy0 = fmaf(y, wy.z, oy0); oz0 = fmaf(y, wz.z, oz0);
      y = fmaxf(fmaf(a0[4*q+3], sc.w, tc.w), 0.f); ox0 = fmaf(y, wx.w, ox0); oy0 = fmaf(y, wy.w, oy0); oz0 = fmaf(y, wz.w, oz0);
      y = fmaxf(fmaf(a1[4*q],   sc.x, tc.x), 0.f); ox1 = fmaf(y, wx.x, ox1); oy1 = fmaf(y, wy.x, oy1); oz1 = fmaf(y, wz.x, oz1);
      y = fmaxf(fmaf(a1[4*q+1], sc.y, tc.y), 0.f); ox1 = fmaf(y, wx.y, ox1); oy1 = fmaf(y, wy.y, oy1); oz1 = fmaf(y, wz.y, oz1);
      y = fmaxf(fmaf(a1[4*q+2], sc.z, tc.z), 0.f); ox1 = fmaf(y, wx.z, ox1); oy1 = fmaf(y, wy.z, oy1); oz1 = fmaf(y, wz.z, oz1);
      y = fmaxf(fmaf(a1[4*q+3], sc.w, tc.w), 0.f); ox1 = fmaf(y, wx.w, ox1); oy1 = fmaf(y, wy.w, oy1); oz1 = fmaf(y, wz.w, oz1);
    }
    size_t o = (size_t)i * 3;
    out_off[o] = ox0; out_off[o + 1] = oy0; out_off[o + 2] = oz0;
    if (has1) {
      size_t o1 = (size_t)i1 * 3;
      out_off[o1] = ox1; out_off[o1 + 1] = oy1; out_off[o1 + 2] = oz1;
    }
  }
}

// ---------------- finalize proposal means ----------------
__global__ void k_finalize(const float* __restrict__ acc,
                           float* __restrict__ psem, float* __restrict__ pbin) {
  int p = blockIdx.x * blockDim.x + threadIdx.x;
  if (p < PPROP) {
    const float* t = acc + p * TBLW;
    float cnt = fmaxf(t[19], 1.f);
    float r = 1.f / cnt;
#pragma unroll
    for (int c = 0; c < 18; c++) psem[p * 18 + c] = t[c] * r;
    pbin[p] = t[18] * r;
  }
}

extern "C" void kernel_launch(void* const* d_in, const int* in_sizes, int n_in,
                              void* d_out, int out_size, void* d_ws, size_t ws_size,
                              hipStream_t stream) {
  const float* feats = (const float*)d_in[0];
  const float* sem   = (const float*)d_in[1];
  const float* bin   = (const float*)d_in[2];
  const int*   pidx  = (const int*)d_in[3];
  const int*   pid   = (const int*)d_in[4];
  const float* W1  = (const float*)d_in[5];
  const float* b1  = (const float*)d_in[6];
  const float* g1  = (const float*)d_in[7];
  const float* be1 = (const float*)d_in[8];
  const float* W2  = (const float*)d_in[9];
  const float* b2  = (const float*)d_in[10];
  const float* Wm1 = (const float*)d_in[11];
  const float* bm1 = (const float*)d_in[12];
  const float* Wm2 = (const float*)d_in[13];
  const float* bm2 = (const float*)d_in[14];
  const float* Wi  = (const float*)d_in[15];
  const float* bi  = (const float*)d_in[16];

  int n = in_sizes[2];   // binary_scores is (N,1)
  int m = in_sizes[3];   // memberships

  float* out = (float*)d_out;
  float* o_scores = out;
  float* o_off  = out + (size_t)n * KCLS;
  float* o_psem = o_off + (size_t)n * 3;
  float* o_pbin = o_psem + (size_t)PPROP * 18;
  float* o_mask = o_pbin + PPROP;
  float* o_iou  = o_mask + n;

  float* stats = (float*)d_ws;         // 64 floats: sum[32], sumsq[32]
  float* bnsc  = stats + 2 * CDIM;     // 32
  float* bntc  = bnsc + CDIM;          // 32
  float* acc   = bntc + CDIM;          // P*TBLW floats

  // zero accumulators every launch (harness does not re-poison between replays)
  hipMemsetAsync(d_ws, 0, (4 * CDIM + PPROP * TBLW) * sizeof(float), stream);

  k_scores  <<<2048, 256, 0, stream>>>(sem, bin, o_scores, n);
  // run scatter right after scores so semantic_scores is L3-resident for the gather
  k_scatter <<<256, 512, 0, stream>>>(sem, bin, pidx, pid, acc, m);
  k_heads   <<<2048, 256, 0, stream>>>(feats, W1, b1, Wm1, bm1, Wm2, bm2, Wi, bi,
                                       o_mask, o_iou, stats, n);
  k_bnprep  <<<1, 64, 0, stream>>>(stats, g1, be1, bnsc, bntc, 1.0f / (float)n);
  k_offsets <<<2048, 256, 0, stream>>>(feats, W1, b1, W2, b2, bnsc, bntc, o_off, n);
  k_finalize<<<4, 256, 0, stream>>>(acc, o_psem, o_pbin);
}

// Round 4
// 1021.410 us; speedup vs baseline: 6.5025x; 6.5025x over previous
//
#include <hip/hip_runtime.h>
#include <hip/hip_bf16.h>

#define CDIM 32
#define KCLS 20
#define NBASE 12
#define PPROP 1024
#define TBLW 20   // 18 sem cols (2..19) + binary + count
#define FPAD 33   // sF row stride: bank (l+c)%32 -> only free 2-way wave64 alias

__device__ __forceinline__ void lds_addf(float* p, float v) {
  __hip_atomic_fetch_add(p, v, __ATOMIC_RELAXED, __HIP_MEMORY_SCOPE_WORKGROUP);
}
__device__ __forceinline__ void glb_addf(float* p, float v) {
  __hip_atomic_fetch_add(p, v, __ATOMIC_RELAXED, __HIP_MEMORY_SCOPE_AGENT);
}

// rolled 32x32 matvec: a[0:32] += f @ W  (W row-major [c][j], staged in LDS)
// '#pragma unroll 1' keeps c runtime -> weight ds_reads cannot be hoisted
// (round-3 lesson: full unroll let the compiler promote 2048 LDS floats to
// registers -> 256 VGPR + 10 GB scratch spill traffic)
__device__ __forceinline__ void mm32(const float* sW, const float* fp, float* a) {
#pragma unroll 1
  for (int c = 0; c < CDIM; ++c) {
    float fc = fp[c];
    const float4* wr = reinterpret_cast<const float4*>(sW + c * CDIM);
#pragma unroll
    for (int q = 0; q < 8; ++q) {
      float4 w = wr[q];
      a[4*q]   = fmaf(fc, w.x, a[4*q]);
      a[4*q+1] = fmaf(fc, w.y, a[4*q+1]);
      a[4*q+2] = fmaf(fc, w.z, a[4*q+2]);
      a[4*q+3] = fmaf(fc, w.w, a[4*q+3]);
    }
  }
}

// ---------------- scores: open-vocab renormalized softmax-gate ----------------
__global__ void k_scores(const float* __restrict__ sem, const float* __restrict__ bin,
                         float* __restrict__ out, int n) {
  int stride = gridDim.x * blockDim.x;
  for (int i = blockIdx.x * blockDim.x + threadIdx.x; i < n; i += stride) {
    const float4* r = reinterpret_cast<const float4*>(sem + (size_t)i * KCLS);
    float s[KCLS];
    float4 v;
    v = r[0]; s[0]=v.x; s[1]=v.y; s[2]=v.z; s[3]=v.w;
    v = r[1]; s[4]=v.x; s[5]=v.y; s[6]=v.z; s[7]=v.w;
    v = r[2]; s[8]=v.x; s[9]=v.y; s[10]=v.z; s[11]=v.w;
    v = r[3]; s[12]=v.x; s[13]=v.y; s[14]=v.z; s[15]=v.w;
    v = r[4]; s[16]=v.x; s[17]=v.y; s[18]=v.z; s[19]=v.w;

    float m12 = s[0];
#pragma unroll
    for (int k = 1; k < NBASE; k++) m12 = fmaxf(m12, s[k]);
    float sum12 = 0.f;
#pragma unroll
    for (int k = 0; k < NBASE; k++) { s[k] = __expf(s[k] - m12); sum12 += s[k]; }

    float m8 = s[NBASE];
#pragma unroll
    for (int k = NBASE + 1; k < KCLS; k++) m8 = fmaxf(m8, s[k]);
    float sum8 = 0.f;
#pragma unroll
    for (int k = NBASE; k < KCLS; k++) { s[k] = __expf(s[k] - m8); sum8 += s[k]; }

    float sig = 1.f / (1.f + __expf(-bin[i]));
    // analytic: renormalization denominator == 1, fold gate/softmax-denoms
    float cb = sig / sum12;
    float cn = (1.f - sig) / sum8;
#pragma unroll
    for (int k = 0; k < NBASE; k++) s[k] *= cb;
#pragma unroll
    for (int k = NBASE; k < KCLS; k++) s[k] *= cn;

    float4* o = reinterpret_cast<float4*>(out + (size_t)i * KCLS);
    o[0] = make_float4(s[0], s[1], s[2], s[3]);
    o[1] = make_float4(s[4], s[5], s[6], s[7]);
    o[2] = make_float4(s[8], s[9], s[10], s[11]);
    o[3] = make_float4(s[12], s[13], s[14], s[15]);
    o[4] = make_float4(s[16], s[17], s[18], s[19]);
  }
}

// ---------------- proposal scatter-mean accumulation ----------------
__global__ __launch_bounds__(512) void k_scatter(const float* __restrict__ sem,
    const float* __restrict__ bin, const int* __restrict__ pidx,
    const int* __restrict__ pid, float* __restrict__ acc, int m) {
  __shared__ float tbl[PPROP * TBLW];  // 80 KiB
  for (int t = threadIdx.x; t < PPROP * TBLW; t += blockDim.x) tbl[t] = 0.f;
  __syncthreads();

  int stride = gridDim.x * blockDim.x;
  for (int i = blockIdx.x * blockDim.x + threadIdx.x; i < m; i += stride) {
    int q = pidx[i];
    int p = pid[i];
    const float* row = sem + (size_t)q * KCLS;
    float2 a  = *reinterpret_cast<const float2*>(row + 2);
    float4 c0 = *reinterpret_cast<const float4*>(row + 4);
    float4 c1 = *reinterpret_cast<const float4*>(row + 8);
    float4 c2 = *reinterpret_cast<const float4*>(row + 12);
    float4 c3 = *reinterpret_cast<const float4*>(row + 16);
    float bv = bin[q];
    float* t = tbl + p * TBLW;
    lds_addf(t + 0, a.x);  lds_addf(t + 1, a.y);
    lds_addf(t + 2, c0.x); lds_addf(t + 3, c0.y); lds_addf(t + 4, c0.z); lds_addf(t + 5, c0.w);
    lds_addf(t + 6, c1.x); lds_addf(t + 7, c1.y); lds_addf(t + 8, c1.z); lds_addf(t + 9, c1.w);
    lds_addf(t +10, c2.x); lds_addf(t +11, c2.y); lds_addf(t +12, c2.z); lds_addf(t +13, c2.w);
    lds_addf(t +14, c3.x); lds_addf(t +15, c3.y); lds_addf(t +16, c3.z); lds_addf(t +17, c3.w);
    lds_addf(t +18, bv);
    lds_addf(t +19, 1.f);
  }
  __syncthreads();
  for (int t = threadIdx.x; t < PPROP * TBLW; t += blockDim.x) {
    float v = tbl[t];
    if (v != 0.f) glb_addf(acc + t, v);
  }
}

// ---------------- mask/iou heads + BN statistics over h1 = feats@W1+b1 ----------------
__global__ __launch_bounds__(256, 1) void k_heads(const float* __restrict__ feats,
    const float* __restrict__ W1,  const float* __restrict__ b1,
    const float* __restrict__ Wm1, const float* __restrict__ bm1,
    const float* __restrict__ Wm2, const float* __restrict__ bm2,
    const float* __restrict__ Wi,  const float* __restrict__ bi,
    float* __restrict__ mask_out, float* __restrict__ iou_out,
    float* __restrict__ stats, int n) {
  __shared__ float sWm1[CDIM * CDIM];
  __shared__ float sW1[CDIM * CDIM];
  __shared__ float sBm1[CDIM], sB1[CDIM], sWm2[CDIM], sWi[CDIM];
  __shared__ float sF[256 * FPAD];   // per-thread feature row (runtime-index safe)
  __shared__ float red[2 * CDIM];

  int t = threadIdx.x;
  for (int idx = t; idx < CDIM * CDIM; idx += 256) { sWm1[idx] = Wm1[idx]; sW1[idx] = W1[idx]; }
  if (t < CDIM) { sBm1[t] = bm1[t]; sB1[t] = b1[t]; sWm2[t] = Wm2[t]; sWi[t] = Wi[t]; }
  __syncthreads();

  const float4* Bm14 = reinterpret_cast<const float4*>(sBm1);
  const float4* B14  = reinterpret_cast<const float4*>(sB1);
  const float4* Wm24 = reinterpret_cast<const float4*>(sWm2);
  const float4* Wi4  = reinterpret_cast<const float4*>(sWi);
  float* myf = sF + t * FPAD;

  float hs[CDIM], hq[CDIM];
#pragma unroll
  for (int j = 0; j < CDIM; j++) { hs[j] = 0.f; hq[j] = 0.f; }

  float bm2v = bm2[0], biv = bi[0];

  int total = gridDim.x * blockDim.x;
  for (int i = blockIdx.x * blockDim.x + t; i < n; i += total) {
    asm volatile("" ::: "memory");   // block cross-iteration hoisting of LDS reads
    // load feature row -> LDS (own row only, no barrier needed); fuse iou dot
    float io = biv;
    const float4* fr = reinterpret_cast<const float4*>(feats + (size_t)i * CDIM);
#pragma unroll
    for (int q = 0; q < 8; q++) {
      float4 v = fr[q];
      myf[4*q] = v.x; myf[4*q+1] = v.y; myf[4*q+2] = v.z; myf[4*q+3] = v.w;
      float4 wi = Wi4[q];
      io = fmaf(v.x, wi.x, io); io = fmaf(v.y, wi.y, io);
      io = fmaf(v.z, wi.z, io); io = fmaf(v.w, wi.w, io);
    }

    // mask head hidden: relu(f @ Wm1 + bm1) . Wm2 + bm2
    float a[CDIM];
#pragma unroll
    for (int q = 0; q < 8; q++) {
      float4 b = Bm14[q];
      a[4*q]=b.x; a[4*q+1]=b.y; a[4*q+2]=b.z; a[4*q+3]=b.w;
    }
    mm32(sWm1, myf, a);
    float mk = bm2v;
#pragma unroll
    for (int q = 0; q < 8; q++) {
      float4 wm = Wm24[q];
      mk = fmaf(fmaxf(a[4*q],   0.f), wm.x, mk);
      mk = fmaf(fmaxf(a[4*q+1], 0.f), wm.y, mk);
      mk = fmaf(fmaxf(a[4*q+2], 0.f), wm.z, mk);
      mk = fmaf(fmaxf(a[4*q+3], 0.f), wm.w, mk);
    }
    mask_out[i] = mk;
    iou_out[i] = io;

    // h1 = f @ W1 + b1 for BN stats (reuse a)
#pragma unroll
    for (int q = 0; q < 8; q++) {
      float4 b = B14[q];
      a[4*q]=b.x; a[4*q+1]=b.y; a[4*q+2]=b.z; a[4*q+3]=b.w;
    }
    mm32(sW1, myf, a);
#pragma unroll
    for (int j = 0; j < CDIM; j++) { hs[j] += a[j]; hq[j] = fmaf(a[j], a[j], hq[j]); }
  }

  __syncthreads();
  for (int q = t; q < 2 * CDIM; q += 256) red[q] = 0.f;
  __syncthreads();
#pragma unroll
  for (int j = 0; j < CDIM; j++) { lds_addf(&red[j], hs[j]); lds_addf(&red[CDIM + j], hq[j]); }
  __syncthreads();
  for (int q = t; q < 2 * CDIM; q += 256) glb_addf(&stats[q], red[q]);
}

// ---------------- tiny: fold BN stats + b1 into scale/shift ----------------
__global__ void k_bnprep(const float* __restrict__ stats,
                         const float* __restrict__ g1, const float* __restrict__ be1,
                         const float* __restrict__ b1,
                         float* __restrict__ bnsc, float* __restrict__ bntc, float invN) {
  int j = threadIdx.x;
  if (j < CDIM) {
    float mu  = stats[j] * invN;
    float var = stats[CDIM + j] * invN - mu * mu;
    float isd = rsqrtf(var + 1e-4f);
    float sc = g1[j] * isd;
    bnsc[j] = sc;
    // y = (a + b1 - mu)*sc + be1, a = f@W1 (bias folded here so k_offsets inits a=0)
    bntc[j] = be1[j] + (b1[j] - mu) * sc;
  }
}

// ---------------- pt_offsets: Linear->BN(precomputed sc/tc)->ReLU->Linear ----------------
__global__ __launch_bounds__(256, 1) void k_offsets(const float* __restrict__ feats,
    const float* __restrict__ W1,
    const float* __restrict__ W2, const float* __restrict__ b2,
    const float* __restrict__ bnsc, const float* __restrict__ bntc,
    float* __restrict__ out_off, int n) {
  __shared__ float sW1[CDIM * CDIM];
  __shared__ float sSc[CDIM], sTc[CDIM];
  __shared__ float sW2x[CDIM], sW2y[CDIM], sW2z[CDIM];
  __shared__ float sF[256 * FPAD];

  int t = threadIdx.x;
  for (int idx = t; idx < CDIM * CDIM; idx += 256) sW1[idx] = W1[idx];
  if (t < CDIM) {
    sSc[t] = bnsc[t]; sTc[t] = bntc[t];
    sW2x[t] = W2[t * 3 + 0]; sW2y[t] = W2[t * 3 + 1]; sW2z[t] = W2[t * 3 + 2];
  }
  __syncthreads();

  const float4* Sc4 = reinterpret_cast<const float4*>(sSc);
  const float4* Tc4 = reinterpret_cast<const float4*>(sTc);
  const float4* Wx4 = reinterpret_cast<const float4*>(sW2x);
  const float4* Wy4 = reinterpret_cast<const float4*>(sW2y);
  const float4* Wz4 = reinterpret_cast<const float4*>(sW2z);
  float* myf = sF + t * FPAD;

  float b2x = b2[0], b2y = b2[1], b2z = b2[2];

  int total = gridDim.x * blockDim.x;
  for (int i = blockIdx.x * blockDim.x + t; i < n; i += total) {
    asm volatile("" ::: "memory");
    const float4* fr = reinterpret_cast<const float4*>(feats + (size_t)i * CDIM);
#pragma unroll
    for (int q = 0; q < 8; q++) {
      float4 v = fr[q];
      myf[4*q] = v.x; myf[4*q+1] = v.y; myf[4*q+2] = v.z; myf[4*q+3] = v.w;
    }

    float a[CDIM];
#pragma unroll
    for (int j = 0; j < CDIM; j++) a[j] = 0.f;
    mm32(sW1, myf, a);

    float ox = b2x, oy = b2y, oz = b2z;
#pragma unroll
    for (int q = 0; q < 8; q++) {
      float4 sc = Sc4[q], tc = Tc4[q];
      float4 wx = Wx4[q], wy = Wy4[q], wz = Wz4[q];
      float y;
      y = fmaxf(fmaf(a[4*q],   sc.x, tc.x), 0.f); ox = fmaf(y, wx.x, ox); oy = fmaf(y, wy.x, oy); oz = fmaf(y, wz.x, oz);
      y = fmaxf(fmaf(a[4*q+1], sc.y, tc.y), 0.f); ox = fmaf(y, wx.y, ox); oy = fmaf(y, wy.y, oy); oz = fmaf(y, wz.y, oz);
      y = fmaxf(fmaf(a[4*q+2], sc.z, tc.z), 0.f); ox = fmaf(y, wx.z, ox); oy = fmaf(y, wy.z, oy); oz = fmaf(y, wz.z, oz);
      y = fmaxf(fmaf(a[4*q+3], sc.w, tc.w), 0.f); ox = fmaf(y, wx.w, ox); oy = fmaf(y, wy.w, oy); oz = fmaf(y, wz.w, oz);
    }
    size_t o = (size_t)i * 3;
    out_off[o] = ox; out_off[o + 1] = oy; out_off[o + 2] = oz;
  }
}

// ---------------- finalize proposal means ----------------
__global__ void k_finalize(const float* __restrict__ acc,
                           float* __restrict__ psem, float* __restrict__ pbin) {
  int p = blockIdx.x * blockDim.x + threadIdx.x;
  if (p < PPROP) {
    const float* t = acc + p * TBLW;
    float cnt = fmaxf(t[19], 1.f);
    float r = 1.f / cnt;
#pragma unroll
    for (int c = 0; c < 18; c++) psem[p * 18 + c] = t[c] * r;
    pbin[p] = t[18] * r;
  }
}

extern "C" void kernel_launch(void* const* d_in, const int* in_sizes, int n_in,
                              void* d_out, int out_size, void* d_ws, size_t ws_size,
                              hipStream_t stream) {
  const float* feats = (const float*)d_in[0];
  const float* sem   = (const float*)d_in[1];
  const float* bin   = (const float*)d_in[2];
  const int*   pidx  = (const int*)d_in[3];
  const int*   pid   = (const int*)d_in[4];
  const float* W1  = (const float*)d_in[5];
  const float* b1  = (const float*)d_in[6];
  const float* g1  = (const float*)d_in[7];
  const float* be1 = (const float*)d_in[8];
  const float* W2  = (const float*)d_in[9];
  const float* b2  = (const float*)d_in[10];
  const float* Wm1 = (const float*)d_in[11];
  const float* bm1 = (const float*)d_in[12];
  const float* Wm2 = (const float*)d_in[13];
  const float* bm2 = (const float*)d_in[14];
  const float* Wi  = (const float*)d_in[15];
  const float* bi  = (const float*)d_in[16];

  int n = in_sizes[2];   // binary_scores is (N,1)
  int m = in_sizes[3];   // memberships

  float* out = (float*)d_out;
  float* o_scores = out;
  float* o_off  = out + (size_t)n * KCLS;
  float* o_psem = o_off + (size_t)n * 3;
  float* o_pbin = o_psem + (size_t)PPROP * 18;
  float* o_mask = o_pbin + PPROP;
  float* o_iou  = o_mask + n;

  float* stats = (float*)d_ws;         // 64 floats: sum[32], sumsq[32]
  float* bnsc  = stats + 2 * CDIM;     // 32
  float* bntc  = bnsc + CDIM;          // 32
  float* acc   = bntc + CDIM;          // P*TBLW floats

  // zero accumulators every launch (harness does not re-poison between replays)
  hipMemsetAsync(d_ws, 0, (4 * CDIM + PPROP * TBLW) * sizeof(float), stream);

  k_scores  <<<2048, 256, 0, stream>>>(sem, bin, o_scores, n);
  // run scatter right after scores so semantic_scores is L3-resident for the gather
  k_scatter <<<256, 512, 0, stream>>>(sem, bin, pidx, pid, acc, m);
  k_heads   <<<2048, 256, 0, stream>>>(feats, W1, b1, Wm1, bm1, Wm2, bm2, Wi, bi,
                                       o_mask, o_iou, stats, n);
  k_bnprep  <<<1, 64, 0, stream>>>(stats, g1, be1, b1, bnsc, bntc, 1.0f / (float)n);
  k_offsets <<<2048, 256, 0, stream>>>(feats, W1, W2, b2, bnsc, bntc, o_off, n);
  k_finalize<<<4, 256, 0, stream>>>(acc, o_psem, o_pbin);
}